// Round 1
// baseline (2405.540 us; speedup 1.0000x reference)
//
#include <hip/hip_runtime.h>
#include <math.h>

#define kH 256
#define kDin 23
#define kR 16
#define LR 0.05f

// ---------------- W2 transpose (once per call, feeds backward matmul) --------
__global__ __launch_bounds__(256) void w2_transpose_kernel(
    const float* __restrict__ W2a, const float* __restrict__ W2b,
    float* __restrict__ Ta, float* __restrict__ Tb)
{
  __shared__ float tile[32][33];
  const float* src = blockIdx.z ? W2b : W2a;
  float* dst = blockIdx.z ? Tb : Ta;
  int bx = blockIdx.x * 32, by = blockIdx.y * 32;
  int lx = threadIdx.x & 31, ly = threadIdx.x >> 5;
  #pragma unroll
  for (int rr = 0; rr < 32; rr += 8)
    tile[ly + rr][lx] = src[(by + ly + rr) * kH + bx + lx];
  __syncthreads();
  #pragma unroll
  for (int rr = 0; rr < 32; rr += 8)
    dst[(bx + ly + rr) * kH + by + lx] = tile[lx][ly + rr];
}

// ---------------- score: s = d/da min(q1(obs,a), q2(obs,a)) ------------------
__global__ __launch_bounds__(256) void score_kernel(
    const float* __restrict__ obs, const float* __restrict__ act,
    const float* __restrict__ W1a, const float* __restrict__ b1a,
    const float* __restrict__ W2a, const float* __restrict__ b2a,
    const float* __restrict__ W3a, const float* __restrict__ b3a,
    const float* __restrict__ W1b, const float* __restrict__ b1b,
    const float* __restrict__ W2b, const float* __restrict__ b2b,
    const float* __restrict__ W3b, const float* __restrict__ b3b,
    const float* __restrict__ W2Ta, const float* __restrict__ W2Tb,
    float* __restrict__ S)
{
  __shared__ __align__(16) float xs[kR][24];
  __shared__ __align__(16) float bufA[kR][kH];   // h1 of current net
  __shared__ __align__(16) float bufB[kR][kH];   // h2*W3 products, then dh2
  __shared__ unsigned char m1s[2][kR][kH];
  __shared__ unsigned char m2s[2][kR][kH];
  __shared__ float qv[2][kR];
  __shared__ float red[kR][16];
  __shared__ float red6[kR][4][6];
  __shared__ int sel[kR];

  const int t = threadIdx.x;
  const long base = (long)blockIdx.x * kR;

  for (int idx = t; idx < kR * kDin; idx += 256) {
    int row = idx / kDin, k = idx - row * kDin;
    long gr = base + row;
    xs[row][k] = (k < 17) ? obs[gr * 17 + k] : act[gr * 6 + (k - 17)];
  }
  if (t < kR) xs[t][23] = 0.f;
  __syncthreads();

  for (int net = 0; net < 2; ++net) {
    const float* W1 = net ? W1b : W1a;
    const float* b1 = net ? b1b : b1a;
    const float* W2 = net ? W2b : W2a;
    const float* b2 = net ? b2b : b2a;
    const float* W3 = net ? W3b : W3a;
    const float* b3 = net ? b3b : b3a;

    float facc[kR];
    {
      float bv = b1[t];
      #pragma unroll
      for (int r = 0; r < kR; ++r) facc[r] = bv;
    }
    #pragma unroll
    for (int k4 = 0; k4 < 24; k4 += 4) {
      float w0 = W1[(k4 + 0) * kH + t];
      float w1 = W1[(k4 + 1) * kH + t];
      float w2 = W1[(k4 + 2) * kH + t];
      float w3 = (k4 + 3 < kDin) ? W1[(k4 + 3) * kH + t] : 0.f;
      #pragma unroll
      for (int r = 0; r < kR; ++r) {
        float4 x = *(const float4*)&xs[r][k4];
        facc[r] = fmaf(x.x, w0, fmaf(x.y, w1, fmaf(x.z, w2, fmaf(x.w, w3, facc[r]))));
      }
    }
    #pragma unroll
    for (int r = 0; r < kR; ++r) {
      float v = facc[r];
      m1s[net][r][t] = (v > 0.f);
      bufA[r][t] = v > 0.f ? v : 0.f;
    }
    __syncthreads();

    {
      float bv = b2[t];
      #pragma unroll
      for (int r = 0; r < kR; ++r) facc[r] = bv;
    }
    for (int r4 = 0; r4 < kH; r4 += 4) {
      float w0 = W2[(r4 + 0) * kH + t];
      float w1 = W2[(r4 + 1) * kH + t];
      float w2 = W2[(r4 + 2) * kH + t];
      float w3 = W2[(r4 + 3) * kH + t];
      #pragma unroll
      for (int r = 0; r < kR; ++r) {
        float4 h = *(const float4*)&bufA[r][r4];
        facc[r] = fmaf(h.x, w0, fmaf(h.y, w1, fmaf(h.z, w2, fmaf(h.w, w3, facc[r]))));
      }
    }
    float w3t = W3[t];
    #pragma unroll
    for (int r = 0; r < kR; ++r) {
      float v = facc[r];
      m2s[net][r][t] = (v > 0.f);
      bufB[r][t] = (v > 0.f ? v : 0.f) * w3t;
    }
    __syncthreads();
    {
      int row = t >> 4, c = t & 15;
      float p = 0.f;
      #pragma unroll
      for (int k = 0; k < 16; ++k) p += bufB[row][c * 16 + k];
      red[row][c] = p;
    }
    __syncthreads();
    if (t < kR) {
      float q = b3[0];
      #pragma unroll
      for (int c = 0; c < 16; ++c) q += red[t][c];
      qv[net][t] = q;
    }
    __syncthreads();
  }

  if (t < kR) sel[t] = (qv[0][t] <= qv[1][t]) ? 0 : 1;
  __syncthreads();

  int selmask = 0;
  #pragma unroll
  for (int r = 0; r < kR; ++r) selmask |= (sel[r] << r);

  {
    float w3at = W3a[t], w3bt = W3b[t];
    #pragma unroll
    for (int r = 0; r < kR; ++r) {
      int sr = (selmask >> r) & 1;
      float w = sr ? w3bt : w3at;
      bufB[r][t] = m2s[sr][r][t] ? w : 0.f;
    }
  }
  __syncthreads();

  float bacc[kR];
  #pragma unroll
  for (int r = 0; r < kR; ++r) bacc[r] = 0.f;
  for (int c4 = 0; c4 < kH; c4 += 4) {
    float a0w = W2Ta[(c4 + 0) * kH + t];
    float a1w = W2Ta[(c4 + 1) * kH + t];
    float a2w = W2Ta[(c4 + 2) * kH + t];
    float a3w = W2Ta[(c4 + 3) * kH + t];
    float b0w = W2Tb[(c4 + 0) * kH + t];
    float b1w = W2Tb[(c4 + 1) * kH + t];
    float b2w = W2Tb[(c4 + 2) * kH + t];
    float b3w = W2Tb[(c4 + 3) * kH + t];
    #pragma unroll
    for (int r = 0; r < kR; ++r) {
      float4 dd = *(const float4*)&bufB[r][c4];
      if (((selmask >> r) & 1) == 0)
        bacc[r] = fmaf(dd.x, a0w, fmaf(dd.y, a1w, fmaf(dd.z, a2w, fmaf(dd.w, a3w, bacc[r]))));
      else
        bacc[r] = fmaf(dd.x, b0w, fmaf(dd.y, b1w, fmaf(dd.z, b2w, fmaf(dd.w, b3w, bacc[r]))));
    }
  }

  {
    const int lane = t & 63, wv = t >> 6;
    for (int r = 0; r < kR; ++r) {
      int sr = (selmask >> r) & 1;
      const float* W1s = sr ? W1b : W1a;
      float dv = m1s[sr][r][t] ? bacc[r] : 0.f;
      float p0 = dv * W1s[(17 + 0) * kH + t];
      float p1 = dv * W1s[(17 + 1) * kH + t];
      float p2 = dv * W1s[(17 + 2) * kH + t];
      float p3 = dv * W1s[(17 + 3) * kH + t];
      float p4 = dv * W1s[(17 + 4) * kH + t];
      float p5 = dv * W1s[(17 + 5) * kH + t];
      #pragma unroll
      for (int off = 32; off > 0; off >>= 1) {
        p0 += __shfl_down(p0, off);
        p1 += __shfl_down(p1, off);
        p2 += __shfl_down(p2, off);
        p3 += __shfl_down(p3, off);
        p4 += __shfl_down(p4, off);
        p5 += __shfl_down(p5, off);
      }
      if (lane == 0) {
        red6[r][wv][0] = p0; red6[r][wv][1] = p1; red6[r][wv][2] = p2;
        red6[r][wv][3] = p3; red6[r][wv][4] = p4; red6[r][wv][5] = p5;
      }
    }
  }
  __syncthreads();
  if (t < kR * 6) {
    int r = t / 6, d = t - r * 6;
    float s = red6[r][0][d] + red6[r][1][d] + red6[r][2][d] + red6[r][3][d];
    S[(base + r) * 6 + d] = s;
  }
}

// ---------------- per-batch SVGD update (RBF + median bandwidth) -------------
__global__ __launch_bounds__(256) void svgd_kernel(
    const float* __restrict__ a_in, const float* __restrict__ S,
    float* __restrict__ a_out, float* __restrict__ logp, int first)
{
  __shared__ float X[32][6];
  __shared__ float Sv[32][6];
  __shared__ float XS[32];
  __shared__ float d2[1024];
  __shared__ float sb[1024];
  __shared__ float gsh;
  const int t = threadIdx.x;
  const int b = blockIdx.x;
  const long base = (long)b * 192;

  if (t < 192) {
    X[t / 6][t % 6] = a_in[base + t];
    Sv[t / 6][t % 6] = S[base + t];
  }
  __syncthreads();
  if (t < 32) {
    float s = 0.f;
    #pragma unroll
    for (int d = 0; d < 6; ++d) s += X[t][d] * Sv[t][d];
    XS[t] = s;
  }
  for (int idx = t; idx < 1024; idx += 256) {
    int i = idx >> 5, j = idx & 31;
    float s = 0.f;
    #pragma unroll
    for (int d = 0; d < 6; ++d) { float df = X[i][d] - X[j][d]; s += df * df; }
    d2[idx] = s; sb[idx] = s;
  }
  __syncthreads();

  // bitonic sort of 1024 dist^2 values (exact median like jnp.median)
  for (int k = 2; k <= 1024; k <<= 1) {
    for (int j = k >> 1; j > 0; j >>= 1) {
      for (int idx = t; idx < 1024; idx += 256) {
        int ixj = idx ^ j;
        if (ixj > idx) {
          float x0 = sb[idx], x1 = sb[ixj];
          bool dir = ((idx & k) == 0);
          if ((x0 > x1) == dir) { sb[idx] = x1; sb[ixj] = x0; }
        }
      }
      __syncthreads();
    }
  }

  if (t == 0) {
    float med = 0.5f * (sb[511] + sb[512]);
    float h = med / logf(33.0f);
    gsh = 1.0f / (2.0f * h + 1e-8f);
  }
  __syncthreads();
  const float g = gsh;
  for (int idx = t; idx < 1024; idx += 256)
    sb[idx] = expf(-g * d2[idx]);   // K
  __syncthreads();

  const int i = t >> 3, l = t & 7;
  float ks0=0,ks1=0,ks2=0,ks3=0,ks4=0,ks5=0;
  float kx0=0,kx1=0,kx2=0,kx3=0,kx4=0,kx5=0;
  float krow=0.f, kd2=0.f, kxs=0.f;
  #pragma unroll
  for (int jj = 0; jj < 4; ++jj) {
    int j = l + 8 * jj;
    float kv = sb[i * 32 + j];
    float dv = d2[i * 32 + j];
    krow += kv; kd2 += kv * dv; kxs += kv * XS[j];
    ks0 += kv * Sv[j][0]; kx0 += kv * X[j][0];
    ks1 += kv * Sv[j][1]; kx1 += kv * X[j][1];
    ks2 += kv * Sv[j][2]; kx2 += kv * X[j][2];
    ks3 += kv * Sv[j][3]; kx3 += kv * X[j][3];
    ks4 += kv * Sv[j][4]; kx4 += kv * X[j][4];
    ks5 += kv * Sv[j][5]; kx5 += kv * X[j][5];
  }
  #pragma unroll
  for (int off = 4; off > 0; off >>= 1) {
    krow += __shfl_down(krow, off, 8);
    kd2  += __shfl_down(kd2,  off, 8);
    kxs  += __shfl_down(kxs,  off, 8);
    ks0 += __shfl_down(ks0, off, 8); kx0 += __shfl_down(kx0, off, 8);
    ks1 += __shfl_down(ks1, off, 8); kx1 += __shfl_down(kx1, off, 8);
    ks2 += __shfl_down(ks2, off, 8); kx2 += __shfl_down(kx2, off, 8);
    ks3 += __shfl_down(ks3, off, 8); kx3 += __shfl_down(kx3, off, 8);
    ks4 += __shfl_down(ks4, off, 8); kx4 += __shfl_down(kx4, off, 8);
    ks5 += __shfl_down(ks5, off, 8); kx5 += __shfl_down(kx5, off, 8);
  }
  if (l == 0) {
    const float inv_n = 1.0f / 32.0f;
    float t1sum = 0.f;
    float p;
    p = (ks0 + 2.f*g*(X[i][0]*krow - kx0)) * inv_n; a_out[base + i*6 + 0] = X[i][0] + LR * p; t1sum += X[i][0] * ks0;
    p = (ks1 + 2.f*g*(X[i][1]*krow - kx1)) * inv_n; a_out[base + i*6 + 1] = X[i][1] + LR * p; t1sum += X[i][1] * ks1;
    p = (ks2 + 2.f*g*(X[i][2]*krow - kx2)) * inv_n; a_out[base + i*6 + 2] = X[i][2] + LR * p; t1sum += X[i][2] * ks2;
    p = (ks3 + 2.f*g*(X[i][3]*krow - kx3)) * inv_n; a_out[base + i*6 + 3] = X[i][3] + LR * p; t1sum += X[i][3] * ks3;
    p = (ks4 + 2.f*g*(X[i][4]*krow - kx4)) * inv_n; a_out[base + i*6 + 4] = X[i][4] + LR * p; t1sum += X[i][4] * ks4;
    p = (ks5 + 2.f*g*(X[i][5]*krow - kx5)) * inv_n; a_out[base + i*6 + 5] = X[i][5] + LR * p; t1sum += X[i][5] * ks5;
    float term1 = (-2.f * g / 31.f) * (t1sum - kxs);
    float term2 = (-2.f * g / 31.f) * (2.f * g * kd2 - 6.f * (krow - 1.f));
    float lp = first ? 0.f : logp[b * 32 + i];
    logp[b * 32 + i] = lp - LR * (term1 + term2);
  }
}

// ---------------- epilogue: tanh squash + logp assembly ----------------------
__global__ __launch_bounds__(256) void final_kernel(
    const float* __restrict__ a, const float* __restrict__ a0,
    const float* __restrict__ logp, float* __restrict__ out)
{
  const int b = blockIdx.x, t = threadIdx.x;
  const long base = (long)b * 192;
  __shared__ float red[32];
  if (t < 192) out[base + t] = tanhf(a[base + t]);
  if (t < 32) {
    const long rb = base + (long)t * 6;
    float s0 = 0.f, st = 0.f;
    #pragma unroll
    for (int d = 0; d < 6; ++d) {
      float x0 = a0[rb + d];
      s0 += x0 * x0;
      float x = a[rb + d];
      float z = -2.f * x;
      float sp = fmaxf(z, 0.f) + log1pf(expf(-fabsf(z)));
      st += 2.f * (0.69314718056f - x - sp);
    }
    float lpn = -3.0f * logf(1.88495559215f) - (0.5f / 0.3f) * s0;
    red[t] = lpn + logp[b * 32 + t] - st;
  }
  __syncthreads();
  if (t == 0) {
    float s = 0.f;
    #pragma unroll
    for (int n = 0; n < 32; ++n) s += red[n];
    out[196608 + b] = s * (1.0f / 32.0f);
  }
}

extern "C" void kernel_launch(void* const* d_in, const int* in_sizes, int n_in,
                              void* d_out, int out_size, void* d_ws, size_t ws_size,
                              hipStream_t stream) {
  const float* obs  = (const float*)d_in[0];
  const float* a0   = (const float*)d_in[1];
  const float* q1W1 = (const float*)d_in[2];
  const float* q1b1 = (const float*)d_in[3];
  const float* q1W2 = (const float*)d_in[4];
  const float* q1b2 = (const float*)d_in[5];
  const float* q1W3 = (const float*)d_in[6];
  const float* q1b3 = (const float*)d_in[7];
  const float* q2W1 = (const float*)d_in[8];
  const float* q2b1 = (const float*)d_in[9];
  const float* q2W2 = (const float*)d_in[10];
  const float* q2b2 = (const float*)d_in[11];
  const float* q2W3 = (const float*)d_in[12];
  const float* q2b3 = (const float*)d_in[13];
  float* ws   = (float*)d_ws;
  float* W2T1 = ws;
  float* W2T2 = W2T1 + 65536;
  float* a_ws = W2T2 + 65536;
  float* Sbuf = a_ws + 196608;
  float* logp = Sbuf + 196608;
  float* out  = (float*)d_out;

  w2_transpose_kernel<<<dim3(8, 8, 2), 256, 0, stream>>>(q1W2, q2W2, W2T1, W2T2);
  const float* ap = a0;
  for (int s = 0; s < 5; ++s) {
    score_kernel<<<2048, 256, 0, stream>>>(obs, ap,
        q1W1, q1b1, q1W2, q1b2, q1W3, q1b3,
        q2W1, q2b1, q2W2, q2b2, q2W3, q2b3,
        W2T1, W2T2, Sbuf);
    svgd_kernel<<<1024, 256, 0, stream>>>(ap, Sbuf, a_ws, logp, s == 0 ? 1 : 0);
    ap = a_ws;
  }
  final_kernel<<<1024, 256, 0, stream>>>(a_ws, a0, logp, out);
}

// Round 2
// 650.683 us; speedup vs baseline: 3.6969x; 3.6969x over previous
//
#include <hip/hip_runtime.h>
#include <math.h>

#define LR 0.05f

typedef __attribute__((ext_vector_type(8))) short short8;
typedef __attribute__((ext_vector_type(4))) float f32x4;

#define MFMA16(a, b, c) __builtin_amdgcn_mfma_f32_16x16x32_bf16(a, b, c, 0, 0, 0)

__device__ __forceinline__ unsigned short f2bf(float v) {
  unsigned int u = __float_as_uint(v);
  u += 0x7fffu + ((u >> 16) & 1u);
  return (unsigned short)(u >> 16);
}

// ---------------- prep: build bf16 weight copies -----------------------------
// W2bf  [h1][h2] (direct), W2Tbf [h2][h1] (transposed),
// W1Tbf [n=256][k=32] (k>=23 zero), W1tail [n=16][k=256] (rows>=6 zero).
__global__ __launch_bounds__(256) void prep_kernel(
    const float* __restrict__ W1a, const float* __restrict__ W1b,
    const float* __restrict__ W2a, const float* __restrict__ W2b,
    unsigned short* __restrict__ W2bfA, unsigned short* __restrict__ W2bfB,
    unsigned short* __restrict__ W2TbfA, unsigned short* __restrict__ W2TbfB,
    unsigned short* __restrict__ W1TbfA, unsigned short* __restrict__ W1TbfB,
    unsigned short* __restrict__ W1tailA, unsigned short* __restrict__ W1tailB)
{
  int i = blockIdx.x * 256 + threadIdx.x;
  if (i < 131072) {
    const float* W2 = (i >> 16) ? W2b : W2a;
    unsigned short* o = (i >> 16) ? W2bfB : W2bfA;
    int j = i & 65535;
    o[j] = f2bf(W2[j]);
  } else if (i < 262144) {
    int i2 = i - 131072;
    const float* W2 = (i2 >> 16) ? W2b : W2a;
    unsigned short* o = (i2 >> 16) ? W2TbfB : W2TbfA;
    int j = i2 & 65535;
    int n = j >> 8, k = j & 255;
    o[j] = f2bf(W2[k * 256 + n]);
  } else if (i < 278528) {
    int i2 = i - 262144;
    const float* W1 = (i2 >> 13) ? W1b : W1a;
    unsigned short* o = (i2 >> 13) ? W1TbfB : W1TbfA;
    int j = i2 & 8191;
    int n = j >> 5, k = j & 31;
    o[j] = (k < 23) ? f2bf(W1[k * 256 + n]) : (unsigned short)0;
  } else if (i < 286720) {
    int i2 = i - 278528;
    const float* W1 = (i2 >> 12) ? W1b : W1a;
    unsigned short* o = (i2 >> 12) ? W1tailB : W1tailA;
    int j = i2 & 4095;
    int d = j >> 8, tt = j & 255;
    o[j] = (d < 6) ? f2bf(W1[(17 + d) * 256 + tt]) : (unsigned short)0;
  }
}

// ---------------- score: s = d/da min(q1(obs,a), q2(obs,a)), MFMA bf16 -------
__global__ __launch_bounds__(256) void score_kernel(
    const float* __restrict__ obs, const float* __restrict__ act,
    const float* __restrict__ b1a, const float* __restrict__ b2a,
    const float* __restrict__ W3a, const float* __restrict__ b3a,
    const float* __restrict__ b1b, const float* __restrict__ b2b,
    const float* __restrict__ W3b, const float* __restrict__ b3b,
    const unsigned short* __restrict__ W2bfA, const unsigned short* __restrict__ W2bfB,
    const unsigned short* __restrict__ W2TbfA, const unsigned short* __restrict__ W2TbfB,
    const unsigned short* __restrict__ W1TbfA, const unsigned short* __restrict__ W1TbfB,
    const unsigned short* __restrict__ W1tailA, const unsigned short* __restrict__ W1tailB,
    float* __restrict__ S)
{
  __shared__ __align__(16) unsigned short buf0[32][264];  // h1a -> dh2a -> dh1 -> dh1a_masked
  __shared__ __align__(16) unsigned short buf1[32][264];  // h1b -> dh2b -> dh1b_masked
  __shared__ __align__(16) unsigned short xsm[32][40];    // x bf16; later redS (2*32*6 f32)
  __shared__ float qpart[2][4][32];
  __shared__ int selsh[32];

  const int t = threadIdx.x;
  const int lane = t & 63, wv = t >> 6, quad = lane >> 4, l16 = lane & 15;
  const int base = blockIdx.x * 32;
  const int ctb = wv * 4;  // this wave's col-tile base (4 tiles of 16 cols)

  // ---- stage x (obs|act, k>=23 zero) as bf16 ----
  for (int idx = t; idx < 32 * 40; idx += 256) {
    int r = idx / 40, k = idx - r * 40;
    float v = 0.f;
    if (k < 17) v = obs[(base + r) * 17 + k];
    else if (k < 23) v = act[(base + r) * 6 + (k - 17)];
    xsm[r][k] = f2bf(v);
  }
  __syncthreads();

  unsigned int m1a_bits = 0, m1b_bits = 0, m2a_bits = 0, m2b_bits = 0;

  for (int net = 0; net < 2; ++net) {
    const unsigned short* W1T = net ? W1TbfB : W1TbfA;
    const unsigned short* W2T = net ? W2TbfB : W2TbfA;
    const float* b1 = net ? b1b : b1a;
    const float* b2 = net ? b2b : b2a;
    const float* W3 = net ? W3b : W3a;
    unsigned short (*hbuf)[264] = net ? buf1 : buf0;

    // ---- h1 = relu(x @ W1 + b1): one K=32 MFMA step per tile ----
    {
      short8 ax0 = *(const short8*)&xsm[l16][quad * 8];
      short8 ax1 = *(const short8*)&xsm[16 + l16][quad * 8];
      #pragma unroll
      for (int c = 0; c < 4; ++c) {
        int col = (ctb + c) * 16 + l16;
        short8 bw = *(const short8*)&W1T[col * 32 + quad * 8];
        f32x4 z = {0.f, 0.f, 0.f, 0.f};
        f32x4 h0 = MFMA16(ax0, bw, z);
        f32x4 h1v = MFMA16(ax1, bw, z);
        float b1v = b1[col];
        #pragma unroll
        for (int g = 0; g < 4; ++g) {
          float v0 = h0[g] + b1v;
          float v1 = h1v[g] + b1v;
          hbuf[quad * 4 + g][col] = (v0 > 0.f) ? f2bf(v0) : (unsigned short)0;
          hbuf[16 + quad * 4 + g][col] = (v1 > 0.f) ? f2bf(v1) : (unsigned short)0;
        }
      }
    }
    __syncthreads();

    // gather relu-mask bits for my column t (column layout, used in backward)
    {
      unsigned int mb = 0;
      #pragma unroll
      for (int r = 0; r < 32; ++r) mb |= (hbuf[r][t] != 0) ? (1u << r) : 0u;
      if (net) m1b_bits = mb; else m1a_bits = mb;
    }

    // ---- h2pre = h1 @ W2 (K=256, 8 steps) ----
    f32x4 acc[2][4];
    #pragma unroll
    for (int rt = 0; rt < 2; ++rt)
      #pragma unroll
      for (int c = 0; c < 4; ++c) acc[rt][c] = (f32x4){0.f, 0.f, 0.f, 0.f};
    for (int k = 0; k < 8; ++k) {
      short8 a0 = *(const short8*)&hbuf[l16][k * 32 + quad * 8];
      short8 a1 = *(const short8*)&hbuf[16 + l16][k * 32 + quad * 8];
      #pragma unroll
      for (int c = 0; c < 4; ++c) {
        int col = (ctb + c) * 16 + l16;
        short8 bw = *(const short8*)&W2T[col * 256 + k * 32 + quad * 8];
        acc[0][c] = MFMA16(a0, bw, acc[0][c]);
        acc[1][c] = MFMA16(a1, bw, acc[1][c]);
      }
    }

    // ---- epilogue: bias+relu, q partials, m2 bits ----
    float pq[2][4] = {{0.f, 0.f, 0.f, 0.f}, {0.f, 0.f, 0.f, 0.f}};
    unsigned int m2 = 0;
    #pragma unroll
    for (int rt = 0; rt < 2; ++rt)
      #pragma unroll
      for (int c = 0; c < 4; ++c) {
        int col = (ctb + c) * 16 + l16;
        float b2v = b2[col], w3v = W3[col];
        #pragma unroll
        for (int g = 0; g < 4; ++g) {
          float v = acc[rt][c][g] + b2v;
          if (v > 0.f) {
            m2 |= 1u << ((rt * 4 + c) * 4 + g);
            pq[rt][g] += v * w3v;
          }
        }
      }
    if (net) m2b_bits = m2; else m2a_bits = m2;
    #pragma unroll
    for (int off = 8; off; off >>= 1) {
      #pragma unroll
      for (int rt = 0; rt < 2; ++rt)
        #pragma unroll
        for (int g = 0; g < 4; ++g)
          pq[rt][g] += __shfl_xor(pq[rt][g], off, 16);
    }
    if (l16 == 0) {
      #pragma unroll
      for (int rt = 0; rt < 2; ++rt)
        #pragma unroll
        for (int g = 0; g < 4; ++g)
          qpart[net][wv][rt * 16 + quad * 4 + g] = pq[rt][g];
    }
    __syncthreads();
  }

  // ---- q assembly + min-selection ----
  if (t < 32) {
    float qa = b3a[0], qb = b3b[0];
    #pragma unroll
    for (int w = 0; w < 4; ++w) { qa += qpart[0][w][t]; qb += qpart[1][w][t]; }
    selsh[t] = (qa <= qb) ? 0 : 1;
  }
  __syncthreads();

  // ---- dh2 (split per net, zero-masked): buf0 = sel==0 ? m2a*W3a : 0, buf1 likewise ----
  #pragma unroll
  for (int rt = 0; rt < 2; ++rt)
    #pragma unroll
    for (int c = 0; c < 4; ++c) {
      int col = (ctb + c) * 16 + l16;
      unsigned short w3abf = f2bf(W3a[col]);
      unsigned short w3bbf = f2bf(W3b[col]);
      #pragma unroll
      for (int g = 0; g < 4; ++g) {
        int row = rt * 16 + quad * 4 + g;
        int s = selsh[row];
        int bit = (rt * 4 + c) * 4 + g;
        buf0[row][col] = (s == 0 && ((m2a_bits >> bit) & 1)) ? w3abf : (unsigned short)0;
        buf1[row][col] = (s == 1 && ((m2b_bits >> bit) & 1)) ? w3bbf : (unsigned short)0;
      }
    }
  __syncthreads();

  // ---- dh1pre = dh2a @ W2a^T + dh2b @ W2b^T ----
  f32x4 bacc[2][4];
  #pragma unroll
  for (int rt = 0; rt < 2; ++rt)
    #pragma unroll
    for (int c = 0; c < 4; ++c) bacc[rt][c] = (f32x4){0.f, 0.f, 0.f, 0.f};
  for (int k = 0; k < 8; ++k) {
    short8 a0A = *(const short8*)&buf0[l16][k * 32 + quad * 8];
    short8 a1A = *(const short8*)&buf0[16 + l16][k * 32 + quad * 8];
    short8 a0B = *(const short8*)&buf1[l16][k * 32 + quad * 8];
    short8 a1B = *(const short8*)&buf1[16 + l16][k * 32 + quad * 8];
    #pragma unroll
    for (int c = 0; c < 4; ++c) {
      int col = (ctb + c) * 16 + l16;
      short8 bwA = *(const short8*)&W2bfA[col * 256 + k * 32 + quad * 8];
      short8 bwB = *(const short8*)&W2bfB[col * 256 + k * 32 + quad * 8];
      bacc[0][c] = MFMA16(a0A, bwA, bacc[0][c]);
      bacc[0][c] = MFMA16(a0B, bwB, bacc[0][c]);
      bacc[1][c] = MFMA16(a1A, bwA, bacc[1][c]);
      bacc[1][c] = MFMA16(a1B, bwB, bacc[1][c]);
    }
  }
  __syncthreads();  // all A reads done before overwrite

  // ---- dh1 (unmasked, bf16) -> buf0 ----
  #pragma unroll
  for (int rt = 0; rt < 2; ++rt)
    #pragma unroll
    for (int c = 0; c < 4; ++c) {
      int col = (ctb + c) * 16 + l16;
      #pragma unroll
      for (int g = 0; g < 4; ++g)
        buf0[rt * 16 + quad * 4 + g][col] = f2bf(bacc[rt][c][g]);
    }
  __syncthreads();

  // ---- column pass: read my column, mask by m1[sel], split per net ----
  unsigned short va[32];
  #pragma unroll
  for (int r = 0; r < 32; ++r) va[r] = buf0[r][t];
  __syncthreads();
  #pragma unroll
  for (int r = 0; r < 32; ++r) {
    int s = selsh[r];
    unsigned int mb = s ? m1b_bits : m1a_bits;
    unsigned short v = ((mb >> r) & 1) ? va[r] : (unsigned short)0;
    buf0[r][t] = (s == 0) ? v : (unsigned short)0;
    buf1[r][t] = (s == 1) ? v : (unsigned short)0;
  }
  __syncthreads();

  // ---- S = dh1a_m @ W1a[17:23]^T + dh1b_m @ W1b[17:23]^T (N=6 padded to 16) ----
  {
    int net = wv >> 1, rt = wv & 1;
    const unsigned short* Wt = net ? W1tailB : W1tailA;
    unsigned short (*db)[264] = net ? buf1 : buf0;
    f32x4 sacc = {0.f, 0.f, 0.f, 0.f};
    for (int k = 0; k < 8; ++k) {
      short8 a = *(const short8*)&db[rt * 16 + l16][k * 32 + quad * 8];
      short8 b = *(const short8*)&Wt[l16 * 256 + k * 32 + quad * 8];
      sacc = MFMA16(a, b, sacc);
    }
    float* redS = (float*)&xsm[0][0];
    if (l16 < 6) {
      #pragma unroll
      for (int g = 0; g < 4; ++g)
        redS[(net * 32 + rt * 16 + quad * 4 + g) * 6 + l16] = sacc[g];
    }
  }
  __syncthreads();
  if (t < 192) {
    int r = t / 6, d = t - r * 6;
    const float* redS = (const float*)&xsm[0][0];
    S[(base + r) * 6 + d] = redS[r * 6 + d] + redS[(32 + r) * 6 + d];
  }
}

// ---------------- per-batch SVGD update (RBF + median bandwidth) -------------
__global__ __launch_bounds__(256) void svgd_kernel(
    const float* __restrict__ a_in, const float* __restrict__ S,
    float* __restrict__ a_out, float* __restrict__ logp, int first)
{
  __shared__ float X[32][6];
  __shared__ float Sv[32][6];
  __shared__ float XS[32];
  __shared__ float d2[1024];
  __shared__ float sb[1024];
  __shared__ float gsh;
  const int t = threadIdx.x;
  const int b = blockIdx.x;
  const long base = (long)b * 192;

  if (t < 192) {
    X[t / 6][t % 6] = a_in[base + t];
    Sv[t / 6][t % 6] = S[base + t];
  }
  __syncthreads();
  if (t < 32) {
    float s = 0.f;
    #pragma unroll
    for (int d = 0; d < 6; ++d) s += X[t][d] * Sv[t][d];
    XS[t] = s;
  }
  for (int idx = t; idx < 1024; idx += 256) {
    int i = idx >> 5, j = idx & 31;
    float s = 0.f;
    #pragma unroll
    for (int d = 0; d < 6; ++d) { float df = X[i][d] - X[j][d]; s += df * df; }
    d2[idx] = s; sb[idx] = s;
  }
  __syncthreads();

  for (int k = 2; k <= 1024; k <<= 1) {
    for (int j = k >> 1; j > 0; j >>= 1) {
      for (int idx = t; idx < 1024; idx += 256) {
        int ixj = idx ^ j;
        if (ixj > idx) {
          float x0 = sb[idx], x1 = sb[ixj];
          bool dir = ((idx & k) == 0);
          if ((x0 > x1) == dir) { sb[idx] = x1; sb[ixj] = x0; }
        }
      }
      __syncthreads();
    }
  }

  if (t == 0) {
    float med = 0.5f * (sb[511] + sb[512]);
    float h = med / logf(33.0f);
    gsh = 1.0f / (2.0f * h + 1e-8f);
  }
  __syncthreads();
  const float g = gsh;
  for (int idx = t; idx < 1024; idx += 256)
    sb[idx] = expf(-g * d2[idx]);
  __syncthreads();

  const int i = t >> 3, l = t & 7;
  float ks0=0,ks1=0,ks2=0,ks3=0,ks4=0,ks5=0;
  float kx0=0,kx1=0,kx2=0,kx3=0,kx4=0,kx5=0;
  float krow=0.f, kd2=0.f, kxs=0.f;
  #pragma unroll
  for (int jj = 0; jj < 4; ++jj) {
    int j = l + 8 * jj;
    float kv = sb[i * 32 + j];
    float dv = d2[i * 32 + j];
    krow += kv; kd2 += kv * dv; kxs += kv * XS[j];
    ks0 += kv * Sv[j][0]; kx0 += kv * X[j][0];
    ks1 += kv * Sv[j][1]; kx1 += kv * X[j][1];
    ks2 += kv * Sv[j][2]; kx2 += kv * X[j][2];
    ks3 += kv * Sv[j][3]; kx3 += kv * X[j][3];
    ks4 += kv * Sv[j][4]; kx4 += kv * X[j][4];
    ks5 += kv * Sv[j][5]; kx5 += kv * X[j][5];
  }
  #pragma unroll
  for (int off = 4; off > 0; off >>= 1) {
    krow += __shfl_down(krow, off, 8);
    kd2  += __shfl_down(kd2,  off, 8);
    kxs  += __shfl_down(kxs,  off, 8);
    ks0 += __shfl_down(ks0, off, 8); kx0 += __shfl_down(kx0, off, 8);
    ks1 += __shfl_down(ks1, off, 8); kx1 += __shfl_down(kx1, off, 8);
    ks2 += __shfl_down(ks2, off, 8); kx2 += __shfl_down(kx2, off, 8);
    ks3 += __shfl_down(ks3, off, 8); kx3 += __shfl_down(kx3, off, 8);
    ks4 += __shfl_down(ks4, off, 8); kx4 += __shfl_down(kx4, off, 8);
    ks5 += __shfl_down(ks5, off, 8); kx5 += __shfl_down(kx5, off, 8);
  }
  if (l == 0) {
    const float inv_n = 1.0f / 32.0f;
    float t1sum = 0.f;
    float p;
    p = (ks0 + 2.f*g*(X[i][0]*krow - kx0)) * inv_n; a_out[base + i*6 + 0] = X[i][0] + LR * p; t1sum += X[i][0] * ks0;
    p = (ks1 + 2.f*g*(X[i][1]*krow - kx1)) * inv_n; a_out[base + i*6 + 1] = X[i][1] + LR * p; t1sum += X[i][1] * ks1;
    p = (ks2 + 2.f*g*(X[i][2]*krow - kx2)) * inv_n; a_out[base + i*6 + 2] = X[i][2] + LR * p; t1sum += X[i][2] * ks2;
    p = (ks3 + 2.f*g*(X[i][3]*krow - kx3)) * inv_n; a_out[base + i*6 + 3] = X[i][3] + LR * p; t1sum += X[i][3] * ks3;
    p = (ks4 + 2.f*g*(X[i][4]*krow - kx4)) * inv_n; a_out[base + i*6 + 4] = X[i][4] + LR * p; t1sum += X[i][4] * ks4;
    p = (ks5 + 2.f*g*(X[i][5]*krow - kx5)) * inv_n; a_out[base + i*6 + 5] = X[i][5] + LR * p; t1sum += X[i][5] * ks5;
    float term1 = (-2.f * g / 31.f) * (t1sum - kxs);
    float term2 = (-2.f * g / 31.f) * (2.f * g * kd2 - 6.f * (krow - 1.f));
    float lp = first ? 0.f : logp[b * 32 + i];
    logp[b * 32 + i] = lp - LR * (term1 + term2);
  }
}

// ---------------- epilogue: tanh squash + logp assembly ----------------------
__global__ __launch_bounds__(256) void final_kernel(
    const float* __restrict__ a, const float* __restrict__ a0,
    const float* __restrict__ logp, float* __restrict__ out)
{
  const int b = blockIdx.x, t = threadIdx.x;
  const long base = (long)b * 192;
  __shared__ float red[32];
  if (t < 192) out[base + t] = tanhf(a[base + t]);
  if (t < 32) {
    const long rb = base + (long)t * 6;
    float s0 = 0.f, st = 0.f;
    #pragma unroll
    for (int d = 0; d < 6; ++d) {
      float x0 = a0[rb + d];
      s0 += x0 * x0;
      float x = a[rb + d];
      float z = -2.f * x;
      float sp = fmaxf(z, 0.f) + log1pf(expf(-fabsf(z)));
      st += 2.f * (0.69314718056f - x - sp);
    }
    float lpn = -3.0f * logf(1.88495559215f) - (0.5f / 0.3f) * s0;
    red[t] = lpn + logp[b * 32 + t] - st;
  }
  __syncthreads();
  if (t == 0) {
    float s = 0.f;
    #pragma unroll
    for (int n = 0; n < 32; ++n) s += red[n];
    out[196608 + b] = s * (1.0f / 32.0f);
  }
}

extern "C" void kernel_launch(void* const* d_in, const int* in_sizes, int n_in,
                              void* d_out, int out_size, void* d_ws, size_t ws_size,
                              hipStream_t stream) {
  const float* obs  = (const float*)d_in[0];
  const float* a0   = (const float*)d_in[1];
  const float* q1W1 = (const float*)d_in[2];
  const float* q1b1 = (const float*)d_in[3];
  const float* q1W2 = (const float*)d_in[4];
  const float* q1b2 = (const float*)d_in[5];
  const float* q1W3 = (const float*)d_in[6];
  const float* q1b3 = (const float*)d_in[7];
  const float* q2W1 = (const float*)d_in[8];
  const float* q2b1 = (const float*)d_in[9];
  const float* q2W2 = (const float*)d_in[10];
  const float* q2b2 = (const float*)d_in[11];
  const float* q2W3 = (const float*)d_in[12];
  const float* q2b3 = (const float*)d_in[13];

  unsigned short* wsu = (unsigned short*)d_ws;
  unsigned short* W2bfA  = wsu;
  unsigned short* W2bfB  = W2bfA + 65536;
  unsigned short* W2TbfA = W2bfB + 65536;
  unsigned short* W2TbfB = W2TbfA + 65536;
  unsigned short* W1TbfA = W2TbfB + 65536;
  unsigned short* W1TbfB = W1TbfA + 8192;
  unsigned short* W1tailA = W1TbfB + 8192;
  unsigned short* W1tailB = W1tailA + 4096;
  float* fws  = (float*)(W1tailB + 4096);
  float* a_ws = fws;
  float* Sbuf = a_ws + 196608;
  float* logp = Sbuf + 196608;
  float* out  = (float*)d_out;

  prep_kernel<<<1120, 256, 0, stream>>>(q1W1, q2W1, q1W2, q2W2,
      W2bfA, W2bfB, W2TbfA, W2TbfB, W1TbfA, W1TbfB, W1tailA, W1tailB);

  const float* ap = a0;
  for (int s = 0; s < 5; ++s) {
    score_kernel<<<1024, 256, 0, stream>>>(obs, ap,
        q1b1, q1b2, q1W3, q1b3,
        q2b1, q2b2, q2W3, q2b3,
        W2bfA, W2bfB, W2TbfA, W2TbfB, W1TbfA, W1TbfB, W1tailA, W1tailB,
        Sbuf);
    svgd_kernel<<<1024, 256, 0, stream>>>(ap, Sbuf, a_ws, logp, s == 0 ? 1 : 0);
    ap = a_ws;
  }
  final_kernel<<<1024, 256, 0, stream>>>(a_ws, a0, logp, out);
}

// Round 3
// 591.179 us; speedup vs baseline: 4.0691x; 1.1007x over previous
//
#include <hip/hip_runtime.h>
#include <math.h>

#define LR 0.05f

typedef __attribute__((ext_vector_type(8))) short short8;
typedef __attribute__((ext_vector_type(4))) float f32x4;

#define MFMA16(a, b, c) __builtin_amdgcn_mfma_f32_16x16x32_bf16(a, b, c, 0, 0, 0)

__device__ __forceinline__ unsigned short f2bf(float v) {
  unsigned int u = __float_as_uint(v);
  u += 0x7fffu + ((u >> 16) & 1u);
  return (unsigned short)(u >> 16);
}

__device__ __forceinline__ void ce2(float& a, float& b, bool asc) {
  float lo = fminf(a, b), hi = fmaxf(a, b);
  a = asc ? lo : hi; b = asc ? hi : lo;
}

__device__ __forceinline__ void shufstage(float* v, int ebase, int j, int k) {
  // element-stride j (>=4) compare-exchange via cross-lane shuffle
  int lm = j >> 2;
  bool amLow = ((ebase & j) == 0);
  bool asc = ((ebase & k) == 0);
  bool keepMin = (amLow == asc);
  #pragma unroll
  for (int m = 0; m < 4; ++m) {
    float pv = __shfl_xor(v[m], lm);
    v[m] = keepMin ? fminf(v[m], pv) : fmaxf(v[m], pv);
  }
}

__device__ __forceinline__ void smallstages(float* v, int ebase, int k) {
  if (k >= 4) {                       // j == 2 (intra-thread)
    bool asc = ((ebase & k) == 0);
    ce2(v[0], v[2], asc); ce2(v[1], v[3], asc);
  }
  bool a01 = (((ebase + 0) & k) == 0);  // j == 1
  bool a23 = (((ebase + 2) & k) == 0);
  ce2(v[0], v[1], a01); ce2(v[2], v[3], a23);
}

__device__ __forceinline__ void ldsstage(float* v, int ebase, int j, int k, float* sbuf) {
  __syncthreads();   // previous readers of sbuf done before overwrite
  #pragma unroll
  for (int m = 0; m < 4; ++m) sbuf[ebase + m] = v[m];
  __syncthreads();
  bool amLow = ((ebase & j) == 0);
  bool asc = ((ebase & k) == 0);
  bool keepMin = (amLow == asc);
  #pragma unroll
  for (int m = 0; m < 4; ++m) {
    float pv = sbuf[(ebase ^ j) + m];
    v[m] = keepMin ? fminf(v[m], pv) : fmaxf(v[m], pv);
  }
}

// ---------------- prep: build bf16 weight copies -----------------------------
__global__ __launch_bounds__(256) void prep_kernel(
    const float* __restrict__ W1a, const float* __restrict__ W1b,
    const float* __restrict__ W2a, const float* __restrict__ W2b,
    unsigned short* __restrict__ W2bfA, unsigned short* __restrict__ W2bfB,
    unsigned short* __restrict__ W2TbfA, unsigned short* __restrict__ W2TbfB,
    unsigned short* __restrict__ W1TbfA, unsigned short* __restrict__ W1TbfB,
    unsigned short* __restrict__ W1tailA, unsigned short* __restrict__ W1tailB)
{
  int i = blockIdx.x * 256 + threadIdx.x;
  if (i < 131072) {
    const float* W2 = (i >> 16) ? W2b : W2a;
    unsigned short* o = (i >> 16) ? W2bfB : W2bfA;
    int j = i & 65535;
    o[j] = f2bf(W2[j]);
  } else if (i < 262144) {
    int i2 = i - 131072;
    const float* W2 = (i2 >> 16) ? W2b : W2a;
    unsigned short* o = (i2 >> 16) ? W2TbfB : W2TbfA;
    int j = i2 & 65535;
    int n = j >> 8, k = j & 255;
    o[j] = f2bf(W2[k * 256 + n]);
  } else if (i < 278528) {
    int i2 = i - 262144;
    const float* W1 = (i2 >> 13) ? W1b : W1a;
    unsigned short* o = (i2 >> 13) ? W1TbfB : W1TbfA;
    int j = i2 & 8191;
    int n = j >> 5, k = j & 31;
    o[j] = (k < 23) ? f2bf(W1[k * 256 + n]) : (unsigned short)0;
  } else if (i < 286720) {
    int i2 = i - 278528;
    const float* W1 = (i2 >> 12) ? W1b : W1a;
    unsigned short* o = (i2 >> 12) ? W1tailB : W1tailA;
    int j = i2 & 4095;
    int d = j >> 8, tt = j & 255;
    o[j] = (d < 6) ? f2bf(W1[(17 + d) * 256 + tt]) : (unsigned short)0;
  }
}

// ---------------- fused: 5 x (score + SVGD) + epilogue, one block per batch --
__global__ __launch_bounds__(256) void fused_kernel(
    const float* __restrict__ obs, const float* __restrict__ a0,
    const float* __restrict__ b1a, const float* __restrict__ b2a,
    const float* __restrict__ W3a, const float* __restrict__ b3a,
    const float* __restrict__ b1b, const float* __restrict__ b2b,
    const float* __restrict__ W3b, const float* __restrict__ b3b,
    const unsigned short* __restrict__ W2bfA, const unsigned short* __restrict__ W2bfB,
    const unsigned short* __restrict__ W2TbfA, const unsigned short* __restrict__ W2TbfB,
    const unsigned short* __restrict__ W1TbfA, const unsigned short* __restrict__ W1TbfB,
    const unsigned short* __restrict__ W1tailA, const unsigned short* __restrict__ W1tailB,
    float* __restrict__ out)
{
  __shared__ __align__(16) unsigned short buf0[32][264];  // h1a/dh2a/dh1; d2s aliases
  __shared__ __align__(16) unsigned short buf1[32][264];  // h1b/dh2b; sort scratch aliases
  __shared__ __align__(16) unsigned short xsm[32][40];    // bf16 x (obs cols persist)
  __shared__ float redS[64][6];
  __shared__ float qpart[2][4][32];
  __shared__ float acur[32][6];
  __shared__ float Svv[32][6];
  __shared__ float XSsh[32];
  __shared__ float logps[32];
  __shared__ float asq[32];
  __shared__ int   selsh[32];
  __shared__ float medsh[2];

  const int t = threadIdx.x;
  const int lane = t & 63, wv = t >> 6, quad = lane >> 4, l16 = lane & 15;
  const int b = blockIdx.x;
  const int base = b * 32;
  const int ctb = wv * 4;
  const long abase = (long)b * 192;

  float* d2s = (float*)&buf0[0][0];
  float* sortbuf = (float*)&buf1[0][0];

  // ---- init: acur = a0, asq, logps, full xsm stage ----
  if (t < 192) { int r = t / 6, d = t - r * 6; acur[r][d] = a0[abase + t]; }
  if (t < 32) {
    float s = 0.f;
    #pragma unroll
    for (int d = 0; d < 6; ++d) { float x0 = a0[abase + t * 6 + d]; s += x0 * x0; }
    asq[t] = s; logps[t] = 0.f;
  }
  for (int idx = t; idx < 32 * 40; idx += 256) {
    int r = idx / 40, k = idx - r * 40;
    float v = 0.f;
    if (k < 17) v = obs[(base + r) * 17 + k];
    else if (k < 23) v = a0[abase + r * 6 + (k - 17)];
    xsm[r][k] = f2bf(v);
  }
  __syncthreads();

  for (int s = 0; s < 5; ++s) {
    if (s > 0) {
      if (t < 192) { int r = t / 6, d = t - r * 6; xsm[r][17 + d] = f2bf(acur[r][d]); }
      __syncthreads();
    }

    // ================= score =================
    unsigned int m1a_bits = 0, m1b_bits = 0, m2a_bits = 0, m2b_bits = 0;

    for (int net = 0; net < 2; ++net) {
      const unsigned short* W1T = net ? W1TbfB : W1TbfA;
      const unsigned short* W2T = net ? W2TbfB : W2TbfA;
      const float* b1 = net ? b1b : b1a;
      const float* b2 = net ? b2b : b2a;
      const float* W3 = net ? W3b : W3a;
      unsigned short (*hbuf)[264] = net ? buf1 : buf0;

      // h1 = relu(x @ W1 + b1)
      {
        short8 ax0 = *(const short8*)&xsm[l16][quad * 8];
        short8 ax1 = *(const short8*)&xsm[16 + l16][quad * 8];
        #pragma unroll
        for (int c = 0; c < 4; ++c) {
          int col = (ctb + c) * 16 + l16;
          short8 bw = *(const short8*)&W1T[col * 32 + quad * 8];
          f32x4 z = {0.f, 0.f, 0.f, 0.f};
          f32x4 h0 = MFMA16(ax0, bw, z);
          f32x4 h1v = MFMA16(ax1, bw, z);
          float b1v = b1[col];
          #pragma unroll
          for (int g = 0; g < 4; ++g) {
            float v0 = h0[g] + b1v;
            float v1 = h1v[g] + b1v;
            hbuf[quad * 4 + g][col] = (v0 > 0.f) ? f2bf(v0) : (unsigned short)0;
            hbuf[16 + quad * 4 + g][col] = (v1 > 0.f) ? f2bf(v1) : (unsigned short)0;
          }
        }
      }
      __syncthreads();

      // relu-mask bits for my column t
      {
        unsigned int mb = 0;
        #pragma unroll
        for (int r = 0; r < 32; ++r) mb |= (hbuf[r][t] != 0) ? (1u << r) : 0u;
        if (net) m1b_bits = mb; else m1a_bits = mb;
      }

      // h2pre = h1 @ W2
      f32x4 acc[2][4];
      #pragma unroll
      for (int rt = 0; rt < 2; ++rt)
        #pragma unroll
        for (int c = 0; c < 4; ++c) acc[rt][c] = (f32x4){0.f, 0.f, 0.f, 0.f};
      for (int k = 0; k < 8; ++k) {
        short8 a0f = *(const short8*)&hbuf[l16][k * 32 + quad * 8];
        short8 a1f = *(const short8*)&hbuf[16 + l16][k * 32 + quad * 8];
        #pragma unroll
        for (int c = 0; c < 4; ++c) {
          int col = (ctb + c) * 16 + l16;
          short8 bw = *(const short8*)&W2T[col * 256 + k * 32 + quad * 8];
          acc[0][c] = MFMA16(a0f, bw, acc[0][c]);
          acc[1][c] = MFMA16(a1f, bw, acc[1][c]);
        }
      }

      // bias+relu, q partials, m2 bits
      float pq[2][4] = {{0.f, 0.f, 0.f, 0.f}, {0.f, 0.f, 0.f, 0.f}};
      unsigned int m2 = 0;
      #pragma unroll
      for (int rt = 0; rt < 2; ++rt)
        #pragma unroll
        for (int c = 0; c < 4; ++c) {
          int col = (ctb + c) * 16 + l16;
          float b2v = b2[col], w3v = W3[col];
          #pragma unroll
          for (int g = 0; g < 4; ++g) {
            float v = acc[rt][c][g] + b2v;
            if (v > 0.f) {
              m2 |= 1u << ((rt * 4 + c) * 4 + g);
              pq[rt][g] += v * w3v;
            }
          }
        }
      if (net) m2b_bits = m2; else m2a_bits = m2;
      #pragma unroll
      for (int off = 8; off; off >>= 1) {
        #pragma unroll
        for (int rt = 0; rt < 2; ++rt)
          #pragma unroll
          for (int g = 0; g < 4; ++g)
            pq[rt][g] += __shfl_xor(pq[rt][g], off, 16);
      }
      if (l16 == 0) {
        #pragma unroll
        for (int rt = 0; rt < 2; ++rt)
          #pragma unroll
          for (int g = 0; g < 4; ++g)
            qpart[net][wv][rt * 16 + quad * 4 + g] = pq[rt][g];
      }
      __syncthreads();
    }

    // q assembly + min-selection
    if (t < 32) {
      float qa = b3a[0], qb = b3b[0];
      #pragma unroll
      for (int w = 0; w < 4; ++w) { qa += qpart[0][w][t]; qb += qpart[1][w][t]; }
      selsh[t] = (qa <= qb) ? 0 : 1;
    }
    __syncthreads();

    // dh2 (split per net, zero-masked)
    #pragma unroll
    for (int rt = 0; rt < 2; ++rt)
      #pragma unroll
      for (int c = 0; c < 4; ++c) {
        int col = (ctb + c) * 16 + l16;
        unsigned short w3abf = f2bf(W3a[col]);
        unsigned short w3bbf = f2bf(W3b[col]);
        #pragma unroll
        for (int g = 0; g < 4; ++g) {
          int row = rt * 16 + quad * 4 + g;
          int sl = selsh[row];
          int bit = (rt * 4 + c) * 4 + g;
          buf0[row][col] = (sl == 0 && ((m2a_bits >> bit) & 1)) ? w3abf : (unsigned short)0;
          buf1[row][col] = (sl == 1 && ((m2b_bits >> bit) & 1)) ? w3bbf : (unsigned short)0;
        }
      }
    __syncthreads();

    // dh1pre = dh2a @ W2a^T + dh2b @ W2b^T
    f32x4 bacc[2][4];
    #pragma unroll
    for (int rt = 0; rt < 2; ++rt)
      #pragma unroll
      for (int c = 0; c < 4; ++c) bacc[rt][c] = (f32x4){0.f, 0.f, 0.f, 0.f};
    for (int k = 0; k < 8; ++k) {
      short8 a0A = *(const short8*)&buf0[l16][k * 32 + quad * 8];
      short8 a1A = *(const short8*)&buf0[16 + l16][k * 32 + quad * 8];
      short8 a0B = *(const short8*)&buf1[l16][k * 32 + quad * 8];
      short8 a1B = *(const short8*)&buf1[16 + l16][k * 32 + quad * 8];
      #pragma unroll
      for (int c = 0; c < 4; ++c) {
        int col = (ctb + c) * 16 + l16;
        short8 bwA = *(const short8*)&W2bfA[col * 256 + k * 32 + quad * 8];
        short8 bwB = *(const short8*)&W2bfB[col * 256 + k * 32 + quad * 8];
        bacc[0][c] = MFMA16(a0A, bwA, bacc[0][c]);
        bacc[0][c] = MFMA16(a0B, bwB, bacc[0][c]);
        bacc[1][c] = MFMA16(a1A, bwA, bacc[1][c]);
        bacc[1][c] = MFMA16(a1B, bwB, bacc[1][c]);
      }
    }
    __syncthreads();

    // dh1 (unmasked, bf16) -> buf0
    #pragma unroll
    for (int rt = 0; rt < 2; ++rt)
      #pragma unroll
      for (int c = 0; c < 4; ++c) {
        int col = (ctb + c) * 16 + l16;
        #pragma unroll
        for (int g = 0; g < 4; ++g)
          buf0[rt * 16 + quad * 4 + g][col] = f2bf(bacc[rt][c][g]);
      }
    __syncthreads();

    // column pass: mask by m1[sel], split per net
    unsigned short va[32];
    #pragma unroll
    for (int r = 0; r < 32; ++r) va[r] = buf0[r][t];
    __syncthreads();
    #pragma unroll
    for (int r = 0; r < 32; ++r) {
      int sl = selsh[r];
      unsigned int mb = sl ? m1b_bits : m1a_bits;
      unsigned short v = ((mb >> r) & 1) ? va[r] : (unsigned short)0;
      buf0[r][t] = (sl == 0) ? v : (unsigned short)0;
      buf1[r][t] = (sl == 1) ? v : (unsigned short)0;
    }
    __syncthreads();

    // S = dh1a_m @ W1a[17:23]^T + dh1b_m @ W1b[17:23]^T
    {
      int net = wv >> 1, rt = wv & 1;
      const unsigned short* Wt = net ? W1tailB : W1tailA;
      unsigned short (*db)[264] = net ? buf1 : buf0;
      f32x4 sacc = {0.f, 0.f, 0.f, 0.f};
      for (int k = 0; k < 8; ++k) {
        short8 a = *(const short8*)&db[rt * 16 + l16][k * 32 + quad * 8];
        short8 bb = *(const short8*)&Wt[l16 * 256 + k * 32 + quad * 8];
        sacc = MFMA16(a, bb, sacc);
      }
      if (l16 < 6) {
        #pragma unroll
        for (int g = 0; g < 4; ++g)
          redS[net * 32 + rt * 16 + quad * 4 + g][l16] = sacc[g];
      }
    }
    __syncthreads();

    // ================= SVGD (in-block) =================
    if (t < 192) { int r = t / 6, d = t - r * 6; Svv[r][d] = redS[r][d] + redS[32 + r][d]; }
    for (int idx = t; idx < 1024; idx += 256) {
      int i = idx >> 5, j = idx & 31;
      float sd = 0.f;
      #pragma unroll
      for (int d = 0; d < 6; ++d) { float df = acur[i][d] - acur[j][d]; sd += df * df; }
      d2s[idx] = sd;
    }
    __syncthreads();
    if (t < 32) {
      float sx = 0.f;
      #pragma unroll
      for (int d = 0; d < 6; ++d) sx += acur[t][d] * Svv[t][d];
      XSsh[t] = sx;
    }

    // register/shuffle bitonic sort of 1024 dist^2 (exact median)
    const int ebase = wv * 256 + (t & 63) * 4;
    float v[4];
    #pragma unroll
    for (int m = 0; m < 4; ++m) v[m] = d2s[ebase + m];
    for (int k = 2; k <= 256; k <<= 1) {
      for (int j = k >> 1; j >= 4; j >>= 1) shufstage(v, ebase, j, k);
      smallstages(v, ebase, k);
    }
    ldsstage(v, ebase, 256, 512, sortbuf);
    for (int j = 128; j >= 4; j >>= 1) shufstage(v, ebase, j, 512);
    smallstages(v, ebase, 512);
    ldsstage(v, ebase, 512, 1024, sortbuf);
    ldsstage(v, ebase, 256, 1024, sortbuf);
    for (int j = 128; j >= 4; j >>= 1) shufstage(v, ebase, j, 1024);
    smallstages(v, ebase, 1024);

    #pragma unroll
    for (int m = 0; m < 4; ++m) {
      int e = ebase + m;
      if (e == 511) medsh[0] = v[m];
      if (e == 512) medsh[1] = v[m];
    }
    __syncthreads();
    float med = 0.5f * (medsh[0] + medsh[1]);
    float g = 1.0f / (2.0f * (med / logf(33.0f)) + 1e-8f);

    // K row-sums
    const int i = t >> 3, l = t & 7;
    float ks0=0,ks1=0,ks2=0,ks3=0,ks4=0,ks5=0;
    float kx0=0,kx1=0,kx2=0,kx3=0,kx4=0,kx5=0;
    float krow=0.f, kd2=0.f, kxs=0.f;
    #pragma unroll
    for (int jj = 0; jj < 4; ++jj) {
      int j = l + 8 * jj;
      float dv = d2s[i * 32 + j];
      float kv = expf(-g * dv);
      krow += kv; kd2 += kv * dv; kxs += kv * XSsh[j];
      ks0 += kv * Svv[j][0]; kx0 += kv * acur[j][0];
      ks1 += kv * Svv[j][1]; kx1 += kv * acur[j][1];
      ks2 += kv * Svv[j][2]; kx2 += kv * acur[j][2];
      ks3 += kv * Svv[j][3]; kx3 += kv * acur[j][3];
      ks4 += kv * Svv[j][4]; kx4 += kv * acur[j][4];
      ks5 += kv * Svv[j][5]; kx5 += kv * acur[j][5];
    }
    #pragma unroll
    for (int off = 4; off > 0; off >>= 1) {
      krow += __shfl_down(krow, off, 8);
      kd2  += __shfl_down(kd2,  off, 8);
      kxs  += __shfl_down(kxs,  off, 8);
      ks0 += __shfl_down(ks0, off, 8); kx0 += __shfl_down(kx0, off, 8);
      ks1 += __shfl_down(ks1, off, 8); kx1 += __shfl_down(kx1, off, 8);
      ks2 += __shfl_down(ks2, off, 8); kx2 += __shfl_down(kx2, off, 8);
      ks3 += __shfl_down(ks3, off, 8); kx3 += __shfl_down(kx3, off, 8);
      ks4 += __shfl_down(ks4, off, 8); kx4 += __shfl_down(kx4, off, 8);
      ks5 += __shfl_down(ks5, off, 8); kx5 += __shfl_down(kx5, off, 8);
    }
    float an0=0,an1=0,an2=0,an3=0,an4=0,an5=0, lpnew=0;
    if (l == 0) {
      const float inv_n = 1.0f / 32.0f;
      float t1sum = 0.f, p;
      p = (ks0 + 2.f*g*(acur[i][0]*krow - kx0)) * inv_n; an0 = acur[i][0] + LR * p; t1sum += acur[i][0] * ks0;
      p = (ks1 + 2.f*g*(acur[i][1]*krow - kx1)) * inv_n; an1 = acur[i][1] + LR * p; t1sum += acur[i][1] * ks1;
      p = (ks2 + 2.f*g*(acur[i][2]*krow - kx2)) * inv_n; an2 = acur[i][2] + LR * p; t1sum += acur[i][2] * ks2;
      p = (ks3 + 2.f*g*(acur[i][3]*krow - kx3)) * inv_n; an3 = acur[i][3] + LR * p; t1sum += acur[i][3] * ks3;
      p = (ks4 + 2.f*g*(acur[i][4]*krow - kx4)) * inv_n; an4 = acur[i][4] + LR * p; t1sum += acur[i][4] * ks4;
      p = (ks5 + 2.f*g*(acur[i][5]*krow - kx5)) * inv_n; an5 = acur[i][5] + LR * p; t1sum += acur[i][5] * ks5;
      float term1 = (-2.f * g / 31.f) * (t1sum - kxs);
      float term2 = (-2.f * g / 31.f) * (2.f * g * kd2 - 6.f * (krow - 1.f));
      lpnew = logps[i] - LR * (term1 + term2);
    }
    __syncthreads();   // all reads of acur done before update
    if (l == 0) {
      acur[i][0] = an0; acur[i][1] = an1; acur[i][2] = an2;
      acur[i][3] = an3; acur[i][4] = an4; acur[i][5] = an5;
      logps[i] = lpnew;
    }
    __syncthreads();
  }

  // ================= epilogue =================
  if (t < 192) { int r = t / 6, d = t - r * 6; out[abase + t] = tanhf(acur[r][d]); }
  if (t < 32) {
    float st = 0.f;
    #pragma unroll
    for (int d = 0; d < 6; ++d) {
      float x = acur[t][d];
      float z = -2.f * x;
      float sp = fmaxf(z, 0.f) + log1pf(expf(-fabsf(z)));
      st += 2.f * (0.69314718056f - x - sp);
    }
    float lpn = -3.0f * logf(1.88495559215f) - (0.5f / 0.3f) * asq[t];
    XSsh[t] = lpn + logps[t] - st;
  }
  __syncthreads();
  if (t == 0) {
    float s = 0.f;
    #pragma unroll
    for (int n = 0; n < 32; ++n) s += XSsh[n];
    out[196608 + b] = s * (1.0f / 32.0f);
  }
}

extern "C" void kernel_launch(void* const* d_in, const int* in_sizes, int n_in,
                              void* d_out, int out_size, void* d_ws, size_t ws_size,
                              hipStream_t stream) {
  const float* obs  = (const float*)d_in[0];
  const float* a0   = (const float*)d_in[1];
  const float* q1W1 = (const float*)d_in[2];
  const float* q1b1 = (const float*)d_in[3];
  const float* q1W2 = (const float*)d_in[4];
  const float* q1b2 = (const float*)d_in[5];
  const float* q1W3 = (const float*)d_in[6];
  const float* q1b3 = (const float*)d_in[7];
  const float* q2W1 = (const float*)d_in[8];
  const float* q2b1 = (const float*)d_in[9];
  const float* q2W2 = (const float*)d_in[10];
  const float* q2b2 = (const float*)d_in[11];
  const float* q2W3 = (const float*)d_in[12];
  const float* q2b3 = (const float*)d_in[13];

  unsigned short* wsu = (unsigned short*)d_ws;
  unsigned short* W2bfA  = wsu;
  unsigned short* W2bfB  = W2bfA + 65536;
  unsigned short* W2TbfA = W2bfB + 65536;
  unsigned short* W2TbfB = W2TbfA + 65536;
  unsigned short* W1TbfA = W2TbfB + 65536;
  unsigned short* W1TbfB = W1TbfA + 8192;
  unsigned short* W1tailA = W1TbfB + 8192;
  unsigned short* W1tailB = W1tailA + 4096;
  float* out  = (float*)d_out;

  prep_kernel<<<1120, 256, 0, stream>>>(q1W1, q2W1, q1W2, q2W2,
      W2bfA, W2bfB, W2TbfA, W2TbfB, W1TbfA, W1TbfB, W1tailA, W1tailB);

  fused_kernel<<<1024, 256, 0, stream>>>(obs, a0,
      q1b1, q1b2, q1W3, q1b3,
      q2b1, q2b2, q2W3, q2b3,
      W2bfA, W2bfB, W2TbfA, W2TbfB, W1TbfA, W1TbfB, W1tailA, W1tailB,
      out);
}